// Round 2
// baseline (13229.607 us; speedup 1.0000x reference)
//
#include <hip/hip_runtime.h>
#include <hip/hip_bf16.h>
#include <math.h>

typedef __bf16 bf16;
typedef __bf16 bf16x8 __attribute__((ext_vector_type(8)));
typedef float  f32x4  __attribute__((ext_vector_type(4)));

#define MFMA16(a, b, c) __builtin_amdgcn_mfma_f32_16x16x32_bf16((a), (b), (c), 0, 0, 0)

// Problem constants
#define BB 64
#define TT 512
#define HH 512
#define G4 2048      // 4*HH gate rows, permuted row' = 4*u + g
#define NROW 32768   // BB*TT, row index r = t*64 + b
// split-triple K widths
#define K3 1536      // 512*3: [hi|hi|lo] weights vs [hi|lo|hi] activations

__device__ __forceinline__ float sigmoidf_(float x) { return 1.0f / (1.0f + expf(-x)); }

// ---------------------------------------------------------------------------
// Padded byte stream: bytes[b][p], p in [0,520): 7x NULL, SOS, payload
// ---------------------------------------------------------------------------
__global__ void pad_bytes(const int* __restrict__ payload, int* __restrict__ bytes) {
    int b = blockIdx.x;
    for (int p = threadIdx.x; p < 520; p += blockDim.x)
        bytes[b * 520 + p] = (p < 7) ? 256 : ((p == 7) ? 257 : payload[b * 512 + p - 8]);
}

// ---------------------------------------------------------------------------
// Z[v][j][m'] = sum_kk Wih0[orig(m')][792 + j*32 + kk] * bemb[v][kk]   (fp32 exact)
// ---------------------------------------------------------------------------
__global__ void build_Z(const float* __restrict__ Wih0, const float* __restrict__ bemb,
                        float* __restrict__ Z) {
    int v = blockIdx.x, j = blockIdx.y;
    __shared__ float e[32];
    if (threadIdx.x < 32) e[threadIdx.x] = bemb[v * 32 + threadIdx.x];
    __syncthreads();
#pragma unroll
    for (int i = 0; i < 8; i++) {
        int mp = threadIdx.x + i * 256;
        int u = mp >> 2, g = mp & 3;
        const float* wr = Wih0 + (size_t)(g * 512 + u) * 1048 + 792 + j * 32;
        float sum = 0.f;
#pragma unroll
        for (int kk = 0; kk < 32; kk++) sum += wr[kk] * e[kk];
        Z[((size_t)(v * 8 + j)) * G4 + mp] = sum;
    }
}

// ---------------------------------------------------------------------------
// ctx_gates[b][m'] = Wih0[orig(m')][0:792] . context[b] + bih0 + bhh0  (fp32 exact)
// ---------------------------------------------------------------------------
__global__ void build_ctxg(const float* __restrict__ ecc, const int* __restrict__ npc,
                           const float* __restrict__ npn,
                           const float* __restrict__ cat0, const float* __restrict__ cat1,
                           const float* __restrict__ cat2,
                           const float* __restrict__ bih0, const float* __restrict__ bhh0,
                           const float* __restrict__ Wih0, float* __restrict__ ctxg) {
    int b = blockIdx.x;
    __shared__ float cs[792];
    for (int k = threadIdx.x; k < 792; k += blockDim.x) {
        float v;
        if (k < 512)       v = ecc[b * 512 + k];
        else if (k < 562)  v = cat0[npc[b * 3 + 0] * 50 + (k - 512)];
        else if (k < 626)  v = cat1[npc[b * 3 + 1] * 64 + (k - 562)];
        else if (k < 776)  v = cat2[npc[b * 3 + 2] * 150 + (k - 626)];
        else               v = npn[b * 16 + (k - 776)];
        cs[k] = v;
    }
    __syncthreads();
#pragma unroll
    for (int i = 0; i < 8; i++) {
        int mp = threadIdx.x + i * 256;
        int u = mp >> 2, g = mp & 3;
        int orow = g * 512 + u;
        const float* wr = Wih0 + (size_t)orow * 1048;
        float sum = bih0[orow] + bhh0[orow];
        for (int k = 0; k < 792; k++) sum += wr[k] * cs[k];
        ctxg[b * G4 + mp] = sum;
    }
}

// ---------------------------------------------------------------------------
// Weight conversions with hi/lo split. Triple layout: [Whi(512) | Whi(512) | Wlo(512)]
// pairs against activation triple [hhi | hlo | hhi]  => Whi*hhi + Whi*hlo + Wlo*hhi.
// ---------------------------------------------------------------------------
__global__ void conv_w0r(const float* __restrict__ Whh0, bf16* __restrict__ W0p) {
    int rp = blockIdx.x; int u = rp >> 2, g = rp & 3;
    const float* src = Whh0 + (size_t)(g * 512 + u) * 512;
    bf16* dst = W0p + (size_t)rp * K3;
    for (int k = threadIdx.x; k < 512; k += blockDim.x) {
        float w = src[k]; bf16 hi = (bf16)w; bf16 lo = (bf16)(w - (float)hi);
        dst[k] = hi; dst[512 + k] = hi; dst[1024 + k] = lo;
    }
}
__global__ void conv_w1(const float* __restrict__ Wih1, const float* __restrict__ Whh1,
                        bf16* __restrict__ W1p) {
    int rp = blockIdx.x; int u = rp >> 2, g = rp & 3;
    const float* s0 = Wih1 + (size_t)(g * 512 + u) * 512;
    const float* s1 = Whh1 + (size_t)(g * 512 + u) * 512;
    bf16* dst = W1p + (size_t)rp * (2 * K3);
    for (int k = threadIdx.x; k < 512; k += blockDim.x) {
        float w0 = s0[k]; bf16 h0 = (bf16)w0; bf16 l0 = (bf16)(w0 - (float)h0);
        dst[k] = h0; dst[512 + k] = h0; dst[1024 + k] = l0;
        float w1 = s1[k]; bf16 h1 = (bf16)w1; bf16 l1 = (bf16)(w1 - (float)h1);
        dst[K3 + k] = h1; dst[K3 + 512 + k] = h1; dst[K3 + 1024 + k] = l1;
    }
}
__global__ void conv_wout(const float* __restrict__ Wout, bf16* __restrict__ Woutp) {
    int r = blockIdx.x;
    const float* src = Wout + (size_t)r * 512;
    bf16* dst = Woutp + (size_t)r * K3;
    for (int k = threadIdx.x; k < 512; k += blockDim.x) {
        float w = src[k]; bf16 hi = (bf16)w; bf16 lo = (bf16)(w - (float)hi);
        dst[k] = hi; dst[512 + k] = hi; dst[1024 + k] = lo;
    }
}
__global__ void conv_bias(const float* __restrict__ bih1, const float* __restrict__ bhh1,
                          float* __restrict__ bias1p) {
    int rp = blockIdx.x * blockDim.x + threadIdx.x;
    if (rp >= G4) return;
    int u = rp >> 2, g = rp & 3; int orow = g * 512 + u;
    bias1p[rp] = bih1[orow] + bhh1[orow];
}

// ---------------------------------------------------------------------------
// Phase B stage: layer0 step s (wgs 0..127) + layer1 step s-1 (wgs 128..255).
// h buffers are [64][1536] triple-plane; c fp32. gx0 = ctxg + gather of 8 Z rows.
// Lane owns (b = bt*16+l15, unit u = rt*4+q); acc regs = gates i,f,g,o.
// ---------------------------------------------------------------------------
__global__ __launch_bounds__(256, 1) void lstm_stage(
        const bf16* __restrict__ W0p, const bf16* __restrict__ W1p,
        const float* __restrict__ bias1p,
        const float* __restrict__ ctxg, const float* __restrict__ Z,
        const int* __restrict__ bytes,
        const bf16* __restrict__ h0r, bf16* __restrict__ h0w,
        const bf16* __restrict__ h1r, bf16* __restrict__ h1w,
        float* __restrict__ c0, float* __restrict__ c1,
        bf16* __restrict__ h2_all, int s) {
    int wg = blockIdx.x, tid = threadIdx.x;
    int bt = tid >> 6, lane = tid & 63, l15 = lane & 15, q = lane >> 4;
    int b = bt * 16 + l15;
    if (wg < 128) {                      // -------- layer 0, t = s
        if (s >= TT) return;
        int t = s, rt = wg;
        const bf16* Ar = W0p + (size_t)(rt * 16 + l15) * K3 + q * 8;
        const bf16* Br = h0r + (size_t)b * K3 + q * 8;
        f32x4 a0 = {0.f,0.f,0.f,0.f}, a1 = a0, a2 = a0;
#pragma unroll
        for (int ks = 0; ks < 16; ks++) {
            a0 = MFMA16(*(const bf16x8*)(Ar + ks * 32),        *(const bf16x8*)(Br + ks * 32),        a0);
            a1 = MFMA16(*(const bf16x8*)(Ar + 512 + ks * 32),  *(const bf16x8*)(Br + 512 + ks * 32),  a1);
            a2 = MFMA16(*(const bf16x8*)(Ar + 1024 + ks * 32), *(const bf16x8*)(Br + 1024 + ks * 32), a2);
        }
        f32x4 acc = a0 + a1 + a2;
        int mbase = rt * 16 + q * 4;
        f32x4 g = *(const f32x4*)&ctxg[b * G4 + mbase];
        const int* bp = bytes + b * 520 + t;
#pragma unroll
        for (int j = 0; j < 8; j++) {
            int v = bp[j];
            g += *(const f32x4*)&Z[((size_t)((v << 3) + j)) * G4 + mbase];
        }
        float gi = acc[0] + g[0], gf = acc[1] + g[1], gg = acc[2] + g[2], go = acc[3] + g[3];
        int u = rt * 4 + q;
        int ci = b * 512 + u;
        float cold = c0[ci];
        float cnew = sigmoidf_(gf) * cold + sigmoidf_(gi) * tanhf(gg);
        c0[ci] = cnew;
        float h = sigmoidf_(go) * tanhf(cnew);
        bf16 hh = (bf16)h; bf16 hl = (bf16)(h - (float)hh);
        bf16* hw = h0w + (size_t)b * K3 + u;
        hw[0] = hh; hw[512] = hl; hw[1024] = hh;
    } else {                             // -------- layer 1, t = s-1
        if (s < 1) return;
        int t = s - 1, rt = wg - 128;
        const bf16* Ar = W1p + (size_t)(rt * 16 + l15) * (2 * K3) + q * 8;
        const bf16* B0 = h0r + (size_t)b * K3 + q * 8;   // h0_t (written stage s-1)
        const bf16* B1 = h1r + (size_t)b * K3 + q * 8;   // h1_{t-1}
        f32x4 a0 = {0.f,0.f,0.f,0.f}, a1 = a0, a2 = a0;
#pragma unroll
        for (int ks = 0; ks < 16; ks++) {
            a0 = MFMA16(*(const bf16x8*)(Ar + ks * 32),        *(const bf16x8*)(B0 + ks * 32),        a0);
            a1 = MFMA16(*(const bf16x8*)(Ar + 512 + ks * 32),  *(const bf16x8*)(B0 + 512 + ks * 32),  a1);
            a2 = MFMA16(*(const bf16x8*)(Ar + 1024 + ks * 32), *(const bf16x8*)(B0 + 1024 + ks * 32), a2);
        }
#pragma unroll
        for (int ks = 0; ks < 16; ks++) {
            a0 = MFMA16(*(const bf16x8*)(Ar + K3 + ks * 32),        *(const bf16x8*)(B1 + ks * 32),        a0);
            a1 = MFMA16(*(const bf16x8*)(Ar + K3 + 512 + ks * 32),  *(const bf16x8*)(B1 + 512 + ks * 32),  a1);
            a2 = MFMA16(*(const bf16x8*)(Ar + K3 + 1024 + ks * 32), *(const bf16x8*)(B1 + 1024 + ks * 32), a2);
        }
        f32x4 acc = a0 + a1 + a2;
        f32x4 bi = *(const f32x4*)&bias1p[rt * 16 + q * 4];
        float gi = acc[0] + bi[0], gf = acc[1] + bi[1], gg = acc[2] + bi[2], go = acc[3] + bi[3];
        int u = rt * 4 + q;
        int ci = b * 512 + u;
        float cold = c1[ci];
        float cnew = sigmoidf_(gf) * cold + sigmoidf_(gi) * tanhf(gg);
        c1[ci] = cnew;
        float h = sigmoidf_(go) * tanhf(cnew);
        bf16 hh = (bf16)h; bf16 hl = (bf16)(h - (float)hh);
        bf16* hw = h1w + (size_t)b * K3 + u;
        hw[0] = hh; hw[512] = hl; hw[1024] = hh;
        bf16* h2 = h2_all + ((size_t)(t * 64 + b)) * K3 + u;
        h2[0] = hh; h2[512] = hl; h2[1024] = hh;
    }
}

// ---------------------------------------------------------------------------
// Phase C: logits[b,t,v] = Woutp[v][0:1536] . h2_all[t*64+b][0:1536] + bout[v]
// (3-term split GEMM, K=1536). 128x128 tile, 4 waves of 64x64.
// ---------------------------------------------------------------------------
__global__ __launch_bounds__(256, 2) void gemm_out(const bf16* __restrict__ Wp,
                                                   const bf16* __restrict__ H2,
                                                   const float* __restrict__ bout,
                                                   float* __restrict__ out) {
    __shared__ bf16 As[128 * 32];
    __shared__ bf16 Bs[128 * 32];
    int mt = blockIdx.x, nt = blockIdx.y;
    int tid = threadIdx.x, wave = tid >> 6, lane = tid & 63;
    int l15 = lane & 15, q = lane >> 4;
    int msub = (wave & 1) * 64, nsub = (wave >> 1) * 64;
    f32x4 acc[4][4] = {};
    const bf16* Abase = Wp + (size_t)(mt * 128) * K3;
    const bf16* Bbase = H2 + (size_t)(nt * 128) * K3;
    for (int ks = 0; ks < K3 / 32; ks++) {
        int k0 = ks * 32;
        __syncthreads();
#pragma unroll
        for (int rnd = 0; rnd < 2; rnd++) {
            int c = tid + rnd * 256;
            int rr = c >> 2, seg = c & 3;
            *(int4*)&As[c * 8] = *(const int4*)&Abase[(size_t)rr * K3 + k0 + seg * 8];
            *(int4*)&Bs[c * 8] = *(const int4*)&Bbase[(size_t)rr * K3 + k0 + seg * 8];
        }
        __syncthreads();
        bf16x8 af[4], bf_[4];
#pragma unroll
        for (int i = 0; i < 4; i++) af[i]  = *(const bf16x8*)&As[(msub + i * 16 + l15) * 32 + q * 8];
#pragma unroll
        for (int j = 0; j < 4; j++) bf_[j] = *(const bf16x8*)&Bs[(nsub + j * 16 + l15) * 32 + q * 8];
#pragma unroll
        for (int i = 0; i < 4; i++)
#pragma unroll
            for (int j = 0; j < 4; j++)
                acc[i][j] = MFMA16(af[i], bf_[j], acc[i][j]);
    }
#pragma unroll
    for (int i = 0; i < 4; i++) {
        int m = mt * 128 + msub + i * 16 + q * 4;     // vocab row
        f32x4 bi = *(const f32x4*)&bout[m];
#pragma unroll
        for (int j = 0; j < 4; j++) {
            int n = nt * 128 + nsub + j * 16 + l15;   // t*64+b
            int t = n >> 6, b = n & 63;
            f32x4 v = acc[i][j] + bi;
            *(f32x4*)&out[((size_t)(b * 512 + t)) * 256 + m] = v;
        }
    }
}

// ---------------------------------------------------------------------------
extern "C" void kernel_launch(void* const* d_in, const int* in_sizes, int n_in,
                              void* d_out, int out_size, void* d_ws, size_t ws_size,
                              hipStream_t stream) {
    const float* ecc   = (const float*)d_in[0];
    const int*   npc   = (const int*)d_in[1];
    const float* npn   = (const float*)d_in[2];
    const int*   payld = (const int*)d_in[3];
    const float* cat0  = (const float*)d_in[4];
    const float* cat1  = (const float*)d_in[5];
    const float* cat2  = (const float*)d_in[6];
    const float* bemb  = (const float*)d_in[7];
    const float* Wih0  = (const float*)d_in[8];
    const float* Whh0  = (const float*)d_in[9];
    const float* bih0  = (const float*)d_in[10];
    const float* bhh0  = (const float*)d_in[11];
    const float* Wih1  = (const float*)d_in[12];
    const float* Whh1  = (const float*)d_in[13];
    const float* bih1  = (const float*)d_in[14];
    const float* bhh1  = (const float*)d_in[15];
    const float* Wout  = (const float*)d_in[16];
    const float* bout  = (const float*)d_in[17];
    float* out = (float*)d_out;

    char* ws = (char*)d_ws;
    size_t off = 0;
    auto alloc = [&](size_t bytes) -> void* {
        void* p = ws + off;
        off = (off + bytes + 255) & ~(size_t)255;
        return p;
    };

    // zeroed state block (contiguous)
    size_t zoff = off;
    float* c0v  = (float*)alloc((size_t)BB * HH * 4);
    float* c1v  = (float*)alloc((size_t)BB * HH * 4);
    bf16* h0s0  = (bf16*)alloc((size_t)BB * K3 * 2);
    bf16* h0s1  = (bf16*)alloc((size_t)BB * K3 * 2);
    bf16* h1s0  = (bf16*)alloc((size_t)BB * K3 * 2);
    bf16* h1s1  = (bf16*)alloc((size_t)BB * K3 * 2);
    size_t zbytes = off - zoff;

    bf16* W0p    = (bf16*)alloc((size_t)G4 * K3 * 2);
    bf16* W1p    = (bf16*)alloc((size_t)G4 * 2 * K3 * 2);
    bf16* Woutp  = (bf16*)alloc((size_t)256 * K3 * 2);
    float* bias1p = (float*)alloc((size_t)G4 * 4);
    float* Z      = (float*)alloc((size_t)260 * 8 * G4 * 4);
    float* ctxg   = (float*)alloc((size_t)BB * G4 * 4);
    int*   bytesb = (int*)alloc((size_t)BB * 520 * 4);
    bf16* h2all   = (bf16*)alloc((size_t)NROW * K3 * 2);

    if (ws_size < off) return;   // out stays zero -> absmax ~0.94 signals this

    hipMemsetAsync(ws + zoff, 0, zbytes, stream);

    pad_bytes <<<BB, 256, 0, stream>>>(payld, bytesb);
    build_Z   <<<dim3(260, 8), 256, 0, stream>>>(Wih0, bemb, Z);
    build_ctxg<<<BB, 256, 0, stream>>>(ecc, npc, npn, cat0, cat1, cat2, bih0, bhh0, Wih0, ctxg);
    conv_w0r  <<<G4, 256, 0, stream>>>(Whh0, W0p);
    conv_w1   <<<G4, 256, 0, stream>>>(Wih1, Whh1, W1p);
    conv_wout <<<256, 256, 0, stream>>>(Wout, Woutp);
    conv_bias <<<8, 256, 0, stream>>>(bih1, bhh1, bias1p);

    for (int s = 0; s <= TT; s++) {
        bf16* h0w = (s & 1) ? h0s1 : h0s0;
        bf16* h0r = (s & 1) ? h0s0 : h0s1;
        bf16* h1w = (s & 1) ? h1s1 : h1s0;
        bf16* h1r = (s & 1) ? h1s0 : h1s1;
        lstm_stage<<<256, 256, 0, stream>>>(W0p, W1p, bias1p, ctxg, Z, bytesb,
                                            h0r, h0w, h1r, h1w, c0v, c1v, h2all, s);
    }

    gemm_out<<<dim3(2, 256), 256, 0, stream>>>(Woutp, h2all, bout, out);
}